// Round 1
// baseline (8299.886 us; speedup 1.0000x reference)
//
#include <hip/hip_runtime.h>

// ---------------- problem constants ----------------
#define BSZ   4096
#define NIN   3072
#define N1    1536
#define N2    256
#define NO    10
#define SEQ   128
#define CH    16            // timesteps per chunk
#define NCHUNK (SEQ/CH)

// dynamics constants (fp32, matching the reference's f64->f32 folding)
#define DVM  0.1f           // DT*TAU_MEM_INV
#define DIS  0.8f           // 1 - DT*TAU_SYN_INV
#define VTH  0.4f

// ---------------- workspace layout (bytes) ----------------
// inp1   : 4096*1536*4           = 25165824
// z1bits : 128*4096*24*8         = 100663296
// a2     : 16*4096*256*4         = 67108864
// v2,i2  : 4096*256*4 each       = 4194304 each
// vl,il  : 4096*10*4 each        = 163840 each
#define OFF_INP1 0
#define OFF_Z1   25165824
#define OFF_A2   125829120
#define OFF_V2   192937984
#define OFF_I2   197132288
#define OFF_VL   201326592
#define OFF_IL   201490432

// ============ GEMM1: inp1 = xf @ W1.T + b1  (4096x3072x1536, fp32) ============
// 64x64 tile, BK=32, 256 threads, 4x4 micro-tile
__global__ __launch_bounds__(256) void gemm1_kernel(
        const float* __restrict__ xf, const float* __restrict__ W1,
        const float* __restrict__ b1, float* __restrict__ inp1) {
    __shared__ float As[32][68];   // [k][m]
    __shared__ float Bs[32][68];   // [k][n]
    const int m0 = blockIdx.x * 64;
    const int n0 = blockIdx.y * 64;
    const int tx = threadIdx.x;
    const int r0 = (tx >> 4) << 2;
    const int c0 = (tx & 15) << 2;
    const int sr = tx >> 2;          // staging row 0..63
    const int sk = (tx & 3) << 3;    // staging k offset {0,8,16,24}

    float acc[4][4] = {};
    const float* aptr = xf + (size_t)(m0 + sr) * NIN + sk;
    const float* bptr = W1 + (size_t)(n0 + sr) * NIN + sk;

    for (int kk = 0; kk < NIN; kk += 32) {
        float4 av0 = *(const float4*)(aptr + kk);
        float4 av1 = *(const float4*)(aptr + kk + 4);
        float4 bv0 = *(const float4*)(bptr + kk);
        float4 bv1 = *(const float4*)(bptr + kk + 4);
        __syncthreads();
        As[sk+0][sr]=av0.x; As[sk+1][sr]=av0.y; As[sk+2][sr]=av0.z; As[sk+3][sr]=av0.w;
        As[sk+4][sr]=av1.x; As[sk+5][sr]=av1.y; As[sk+6][sr]=av1.z; As[sk+7][sr]=av1.w;
        Bs[sk+0][sr]=bv0.x; Bs[sk+1][sr]=bv0.y; Bs[sk+2][sr]=bv0.z; Bs[sk+3][sr]=bv0.w;
        Bs[sk+4][sr]=bv1.x; Bs[sk+5][sr]=bv1.y; Bs[sk+6][sr]=bv1.z; Bs[sk+7][sr]=bv1.w;
        __syncthreads();
        #pragma unroll
        for (int k = 0; k < 32; k++) {
            float a[4], b[4];
            *(float4*)a = *(const float4*)&As[k][r0];
            *(float4*)b = *(const float4*)&Bs[k][c0];
            #pragma unroll
            for (int i = 0; i < 4; i++)
                #pragma unroll
                for (int j = 0; j < 4; j++)
                    acc[i][j] += a[i] * b[j];
        }
    }
    float4 bias = *(const float4*)&b1[n0 + c0];
    #pragma unroll
    for (int i = 0; i < 4; i++) {
        float4 o;
        o.x = acc[i][0] + bias.x; o.y = acc[i][1] + bias.y;
        o.z = acc[i][2] + bias.z; o.w = acc[i][3] + bias.w;
        *(float4*)&inp1[(size_t)(m0 + r0 + i) * N1 + n0 + c0] = o;
    }
}

// ============ LIF1: all 128 timesteps, spikes packed to bits ============
// one thread per (b,n); wave ballot packs 64 n's into one uint64
__global__ __launch_bounds__(256) void lif1_kernel(
        const float* __restrict__ inp1, unsigned long long* __restrict__ z1bits) {
    const int b = blockIdx.y;
    const int n = blockIdx.x * 256 + threadIdx.x;
    const int lane = threadIdx.x & 63;
    const int w = n >> 6;                    // word index 0..23
    const float inp = inp1[(size_t)b * N1 + n];
    const size_t obase = (size_t)b * 24 + w;
    float v = 0.f, i = 0.f;
    for (int t = 0; t < SEQ; t++) {
        float vd = v + DVM * (i - v);
        bool z = (vd - VTH) > 0.f;
        unsigned long long m = __ballot(z);
        if (lane == 0) z1bits[(size_t)t * (BSZ * 24) + obase] = m;
        v = z ? 0.f : vd;
        i = DIS * i + inp;
    }
}

// ============ GEMM2: a2[tl,b,:] = z1[t,b,:] @ W2.T + b2  (bit A, fp32) ============
// M = CH*4096 rows (t-major), N=256, K=1536. 64x64 tile, BK=64 (one uint64 word)
__global__ __launch_bounds__(256) void gemm2_kernel(
        const unsigned long long* __restrict__ z1bits,
        const float* __restrict__ W2, const float* __restrict__ b2,
        float* __restrict__ a2, int c) {
    __shared__ unsigned long long Ab[64];
    __shared__ float Ws[64][68];             // [k][o]
    const int gx = blockIdx.x;               // 0..(CH*64-1)
    const int t_l = gx >> 6;
    const int b0 = (gx & 63) << 6;
    const int o0 = blockIdx.y << 6;
    const int t = c * CH + t_l;
    const int tx = threadIdx.x;
    const int r0 = (tx >> 4) << 2;
    const int c0 = (tx & 15) << 2;
    const int so = tx >> 2;                  // staging o row 0..63
    const int sk = (tx & 3) << 4;            // staging k offset {0,16,32,48}
    float acc[4][4] = {};
    const size_t zbase = ((size_t)t * BSZ + b0) * 24;

    for (int w = 0; w < 24; w++) {
        unsigned long long ab = 0;
        if (tx < 64) ab = z1bits[zbase + (size_t)tx * 24 + w];
        const float* wp = W2 + (size_t)(o0 + so) * N1 + (w << 6) + sk;
        float4 wv0 = *(const float4*)(wp);
        float4 wv1 = *(const float4*)(wp + 4);
        float4 wv2 = *(const float4*)(wp + 8);
        float4 wv3 = *(const float4*)(wp + 12);
        __syncthreads();
        if (tx < 64) Ab[tx] = ab;
        Ws[sk+ 0][so]=wv0.x; Ws[sk+ 1][so]=wv0.y; Ws[sk+ 2][so]=wv0.z; Ws[sk+ 3][so]=wv0.w;
        Ws[sk+ 4][so]=wv1.x; Ws[sk+ 5][so]=wv1.y; Ws[sk+ 6][so]=wv1.z; Ws[sk+ 7][so]=wv1.w;
        Ws[sk+ 8][so]=wv2.x; Ws[sk+ 9][so]=wv2.y; Ws[sk+10][so]=wv2.z; Ws[sk+11][so]=wv2.w;
        Ws[sk+12][so]=wv3.x; Ws[sk+13][so]=wv3.y; Ws[sk+14][so]=wv3.z; Ws[sk+15][so]=wv3.w;
        __syncthreads();
        unsigned long long rw0 = Ab[r0+0], rw1 = Ab[r0+1], rw2 = Ab[r0+2], rw3 = Ab[r0+3];
        #pragma unroll
        for (int kh = 0; kh < 2; kh++) {
            unsigned int bb0 = (unsigned int)(rw0 >> (kh*32));
            unsigned int bb1 = (unsigned int)(rw1 >> (kh*32));
            unsigned int bb2 = (unsigned int)(rw2 >> (kh*32));
            unsigned int bb3 = (unsigned int)(rw3 >> (kh*32));
            #pragma unroll
            for (int k2 = 0; k2 < 32; k2++) {
                const int k = kh*32 + k2;
                float wv[4];
                *(float4*)wv = *(const float4*)&Ws[k][c0];
                float a0v = (float)((bb0 >> k2) & 1u);
                float a1v = (float)((bb1 >> k2) & 1u);
                float a2v = (float)((bb2 >> k2) & 1u);
                float a3v = (float)((bb3 >> k2) & 1u);
                #pragma unroll
                for (int j = 0; j < 4; j++) {
                    acc[0][j] += a0v * wv[j];
                    acc[1][j] += a1v * wv[j];
                    acc[2][j] += a2v * wv[j];
                    acc[3][j] += a3v * wv[j];
                }
            }
        }
    }
    float4 bias = *(const float4*)&b2[o0 + c0];
    #pragma unroll
    for (int i = 0; i < 4; i++) {
        float4 o;
        o.x = acc[i][0] + bias.x; o.y = acc[i][1] + bias.y;
        o.z = acc[i][2] + bias.z; o.w = acc[i][3] + bias.w;
        *(float4*)&a2[((size_t)t_l * BSZ + b0 + r0 + i) * N2 + o0 + c0] = o;
    }
}

// ============ LIF2 + LI + max: one block per batch, CH sequential steps ============
__global__ __launch_bounds__(256) void lif2_kernel(
        const float* __restrict__ a2, const float* __restrict__ W3,
        const float* __restrict__ b3, const float* __restrict__ noise,
        float* __restrict__ v2s, float* __restrict__ i2s,
        float* __restrict__ vls, float* __restrict__ ils,
        float* __restrict__ outmax, int c) {
    const int b = blockIdx.x;
    const int n = threadIdx.x;
    const int wid = n >> 6;
    const int lane = n & 63;
    __shared__ float part[4][NO];

    float w3r[NO];
    #pragma unroll
    for (int o = 0; o < NO; o++) w3r[o] = W3[o * N2 + n];

    float v2, i2;
    if (c == 0) { v2 = 0.f; i2 = 0.f; }
    else { v2 = v2s[(size_t)b * N2 + n]; i2 = i2s[(size_t)b * N2 + n]; }
    float vl = 0.f, il = 0.f, mx = -1e30f;
    if (n < NO && c > 0) { vl = vls[b*NO+n]; il = ils[b*NO+n]; mx = outmax[b*NO+n]; }

    for (int tl = 0; tl < CH; tl++) {
        float a2v = a2[((size_t)tl * BSZ + b) * N2 + n];
        float vd = v2 + DVM * (i2 - v2);
        bool z = (vd - VTH) > 0.f;
        v2 = z ? 0.f : vd;
        i2 = DIS * i2 + a2v;

        float cv[NO];
        #pragma unroll
        for (int o = 0; o < NO; o++) cv[o] = z ? w3r[o] : 0.f;
        #pragma unroll
        for (int s = 32; s > 0; s >>= 1)
            #pragma unroll
            for (int o = 0; o < NO; o++) cv[o] += __shfl_xor(cv[o], s, 64);
        if (lane == 0) {
            #pragma unroll
            for (int o = 0; o < NO; o++) part[wid][o] = cv[o];
        }
        __syncthreads();
        if (n < NO) {
            float a3 = part[0][n] + part[1][n] + part[2][n] + part[3][n] + b3[n];
            float vln = vl + DVM * (il - vl);     // uses OLD il
            il = DIS * il + a3;
            vl = vln;
            const int tg = c * CH + tl;
            float ov = vl + 0.001f * noise[((size_t)tg * BSZ + b) * NO + n];
            mx = fmaxf(mx, ov);
        }
        __syncthreads();
    }
    v2s[(size_t)b * N2 + n] = v2;
    i2s[(size_t)b * N2 + n] = i2;
    if (n < NO) { vls[b*NO+n] = vl; ils[b*NO+n] = il; outmax[b*NO+n] = mx; }
}

// ---------------- host ----------------
extern "C" void kernel_launch(void* const* d_in, const int* in_sizes, int n_in,
                              void* d_out, int out_size, void* d_ws, size_t ws_size,
                              hipStream_t stream) {
    const float* x     = (const float*)d_in[0];
    const float* W1    = (const float*)d_in[1];
    const float* b1    = (const float*)d_in[2];
    const float* W2    = (const float*)d_in[3];
    const float* b2    = (const float*)d_in[4];
    const float* W3    = (const float*)d_in[5];
    const float* b3    = (const float*)d_in[6];
    const float* noise = (const float*)d_in[7];
    float* out = (float*)d_out;

    char* ws = (char*)d_ws;
    float* inp1 = (float*)(ws + OFF_INP1);
    unsigned long long* z1 = (unsigned long long*)(ws + OFF_Z1);
    float* a2 = (float*)(ws + OFF_A2);
    float* v2 = (float*)(ws + OFF_V2);
    float* i2 = (float*)(ws + OFF_I2);
    float* vl = (float*)(ws + OFF_VL);
    float* il = (float*)(ws + OFF_IL);

    dim3 blk(256);
    gemm1_kernel<<<dim3(BSZ/64, N1/64), blk, 0, stream>>>(x, W1, b1, inp1);
    lif1_kernel<<<dim3(N1/256, BSZ), blk, 0, stream>>>(inp1, z1);
    for (int c = 0; c < NCHUNK; c++) {
        gemm2_kernel<<<dim3(CH*64, N2/64), blk, 0, stream>>>(z1, W2, b2, a2, c);
        lif2_kernel<<<dim3(BSZ), blk, 0, stream>>>(a2, W3, b3, noise, v2, i2, vl, il, out, c);
    }
}

// Round 2
// 4228.116 us; speedup vs baseline: 1.9630x; 1.9630x over previous
//
#include <hip/hip_runtime.h>

// ---------------- problem constants ----------------
#define BSZ   4096
#define NIN   3072
#define N1    1536
#define N2    256
#define NO    10
#define SEQ   128
#define CH    16            // timesteps per chunk
#define NCHUNK (SEQ/CH)

// dynamics constants
#define DVM  0.1f           // DT*TAU_MEM_INV
#define DIS  0.8f           // 1 - DT*TAU_SYN_INV
#define VTH  0.4f

// ---------------- workspace layout (bytes) ----------------
#define OFF_INP1 0
#define OFF_Z1   25165824
#define OFF_A2   125829120
#define OFF_V2   192937984
#define OFF_I2   197132288
#define OFF_VL   201326592
#define OFF_IL   201490432
#define OFF_W2H  201654272
#define OFF_W2L  202440704
// end ~203.2 MB

typedef short bf16x8 __attribute__((ext_vector_type(8)));
typedef float f32x4  __attribute__((ext_vector_type(4)));

// ============ GEMM1: inp1 = xf @ W1.T + b1  (4096x3072x1536, fp32) ============
__global__ __launch_bounds__(256) void gemm1_kernel(
        const float* __restrict__ xf, const float* __restrict__ W1,
        const float* __restrict__ b1, float* __restrict__ inp1) {
    __shared__ float As[32][68];   // [k][m]
    __shared__ float Bs[32][68];   // [k][n]
    const int m0 = blockIdx.x * 64;
    const int n0 = blockIdx.y * 64;
    const int tx = threadIdx.x;
    const int r0 = (tx >> 4) << 2;
    const int c0 = (tx & 15) << 2;
    const int sr = tx >> 2;
    const int sk = (tx & 3) << 3;

    float acc[4][4] = {};
    const float* aptr = xf + (size_t)(m0 + sr) * NIN + sk;
    const float* bptr = W1 + (size_t)(n0 + sr) * NIN + sk;

    for (int kk = 0; kk < NIN; kk += 32) {
        float4 av0 = *(const float4*)(aptr + kk);
        float4 av1 = *(const float4*)(aptr + kk + 4);
        float4 bv0 = *(const float4*)(bptr + kk);
        float4 bv1 = *(const float4*)(bptr + kk + 4);
        __syncthreads();
        As[sk+0][sr]=av0.x; As[sk+1][sr]=av0.y; As[sk+2][sr]=av0.z; As[sk+3][sr]=av0.w;
        As[sk+4][sr]=av1.x; As[sk+5][sr]=av1.y; As[sk+6][sr]=av1.z; As[sk+7][sr]=av1.w;
        Bs[sk+0][sr]=bv0.x; Bs[sk+1][sr]=bv0.y; Bs[sk+2][sr]=bv0.z; Bs[sk+3][sr]=bv0.w;
        Bs[sk+4][sr]=bv1.x; Bs[sk+5][sr]=bv1.y; Bs[sk+6][sr]=bv1.z; Bs[sk+7][sr]=bv1.w;
        __syncthreads();
        #pragma unroll
        for (int k = 0; k < 32; k++) {
            float a[4], b[4];
            *(float4*)a = *(const float4*)&As[k][r0];
            *(float4*)b = *(const float4*)&Bs[k][c0];
            #pragma unroll
            for (int i = 0; i < 4; i++)
                #pragma unroll
                for (int j = 0; j < 4; j++)
                    acc[i][j] += a[i] * b[j];
        }
    }
    float4 bias = *(const float4*)&b1[n0 + c0];
    #pragma unroll
    for (int i = 0; i < 4; i++) {
        float4 o;
        o.x = acc[i][0] + bias.x; o.y = acc[i][1] + bias.y;
        o.z = acc[i][2] + bias.z; o.w = acc[i][3] + bias.w;
        *(float4*)&inp1[(size_t)(m0 + r0 + i) * N1 + n0 + c0] = o;
    }
}

// ============ LIF1: all 128 timesteps, spikes packed to bits ============
__global__ __launch_bounds__(256) void lif1_kernel(
        const float* __restrict__ inp1, unsigned long long* __restrict__ z1bits) {
    const int b = blockIdx.y;
    const int n = blockIdx.x * 256 + threadIdx.x;
    const int lane = threadIdx.x & 63;
    const int w = n >> 6;
    const float inp = inp1[(size_t)b * N1 + n];
    const size_t obase = (size_t)b * 24 + w;
    float v = 0.f, i = 0.f;
    for (int t = 0; t < SEQ; t++) {
        float vd = v + DVM * (i - v);
        bool z = (vd - VTH) > 0.f;
        unsigned long long m = __ballot(z);
        if (lane == 0) z1bits[(size_t)t * (BSZ * 24) + obase] = m;
        v = z ? 0.f : vd;
        i = DIS * i + inp;
    }
}

// ============ W2 split prep: W2 = hi(bf16) + lo(bf16 residual) ============
__global__ __launch_bounds__(256) void prep_w2_kernel(
        const float* __restrict__ W2,
        unsigned short* __restrict__ hi, unsigned short* __restrict__ lo) {
    const int i = blockIdx.x * 256 + threadIdx.x;
    float w = W2[i];
    unsigned int u = __float_as_uint(w);
    unsigned int rh = (u + 0x7FFFu + ((u >> 16) & 1u)) >> 16;   // RNE to bf16
    hi[i] = (unsigned short)rh;
    float fh = __uint_as_float(rh << 16);
    float r = w - fh;
    unsigned int u2 = __float_as_uint(r);
    unsigned int rl = (u2 + 0x7FFFu + ((u2 >> 16) & 1u)) >> 16;
    lo[i] = (unsigned short)rl;
}

// byte (8 spike bits) -> 8 bf16 {0.0, 1.0} packed for MFMA A-fragment
__device__ __forceinline__ bf16x8 expand8(unsigned int byte) {
    union { unsigned int u[4]; bf16x8 v; } r;
    #pragma unroll
    for (int p = 0; p < 4; p++) {
        unsigned int lo = ((byte >> (2*p)) & 1u) * 0x3F80u;
        unsigned int hi = ((byte >> (2*p+1)) & 1u) * 0x3F80u;
        r.u[p] = lo | (hi << 16);
    }
    return r.v;
}

// ============ GEMM2 via MFMA: a2 = z1 @ (W2hi+W2lo).T + b2 ============
// block: 256 thr = 4 waves; tile 128M x 256N; wave = 64M x 128N
// K-step = 64 (one uint64 spike word). A expanded in-register; B from global (L2-hot).
__global__ __launch_bounds__(256, 2) void gemm2_mfma(
        const unsigned long long* __restrict__ z1bits,
        const unsigned short* __restrict__ W2h, const unsigned short* __restrict__ W2l,
        const float* __restrict__ b2, float* __restrict__ a2, int c) {
    const int tx   = threadIdx.x;
    const int wave = tx >> 6, lane = tx & 63;
    const int wm = wave >> 1, wn = wave & 1;
    const int ko = lane >> 4, ln = lane & 15;
    const int blk = blockIdx.x;            // 0..511
    const int t_l = blk >> 5;              // 0..15
    const int b0  = (blk & 31) * 128 + wm * 64;
    const int t   = c * CH + t_l;
    const int o0  = wn * 128;

    f32x4 acc[4][8];
    const f32x4 zero = {0.f, 0.f, 0.f, 0.f};
    #pragma unroll
    for (int mt = 0; mt < 4; mt++)
        #pragma unroll
        for (int nt = 0; nt < 8; nt++) acc[mt][nt] = zero;

    const size_t zrow = ((size_t)t * BSZ + b0 + ln) * 24;
    const unsigned short* bhp = W2h + (size_t)(o0 + ln) * N1 + ko * 8;
    const unsigned short* blp = W2l + (size_t)(o0 + ln) * N1 + ko * 8;

    for (int w = 0; w < 24; w++) {
        bf16x8 af[4][2];
        #pragma unroll
        for (int mt = 0; mt < 4; mt++) {
            unsigned long long word = z1bits[zrow + (size_t)(mt * 16) * 24 + w];
            unsigned int wlo = (unsigned int)word;
            unsigned int whi = (unsigned int)(word >> 32);
            af[mt][0] = expand8((wlo >> (ko * 8)) & 0xFFu);
            af[mt][1] = expand8((whi >> (ko * 8)) & 0xFFu);
        }
        #pragma unroll
        for (int s = 0; s < 2; s++) {
            #pragma unroll
            for (int nt = 0; nt < 8; nt++) {
                bf16x8 bf = *(const bf16x8*)(bhp + (size_t)(nt * 16) * N1 + w * 64 + s * 32);
                #pragma unroll
                for (int mt = 0; mt < 4; mt++)
                    acc[mt][nt] = __builtin_amdgcn_mfma_f32_16x16x32_bf16(af[mt][s], bf, acc[mt][nt], 0, 0, 0);
            }
            #pragma unroll
            for (int nt = 0; nt < 8; nt++) {
                bf16x8 bf = *(const bf16x8*)(blp + (size_t)(nt * 16) * N1 + w * 64 + s * 32);
                #pragma unroll
                for (int mt = 0; mt < 4; mt++)
                    acc[mt][nt] = __builtin_amdgcn_mfma_f32_16x16x32_bf16(af[mt][s], bf, acc[mt][nt], 0, 0, 0);
            }
        }
    }
    // epilogue: C/D layout col=lane&15, row=(lane>>4)*4+r  [verified m89/m91]
    #pragma unroll
    for (int nt = 0; nt < 8; nt++) {
        const int o = o0 + nt * 16 + ln;
        const float bias = b2[o];
        #pragma unroll
        for (int mt = 0; mt < 4; mt++) {
            #pragma unroll
            for (int r = 0; r < 4; r++) {
                const int brow = b0 + mt * 16 + ko * 4 + r;
                a2[((size_t)t_l * BSZ + brow) * N2 + o] = acc[mt][nt][r] + bias;
            }
        }
    }
}

// ============ LIF2 + LI + max: one block per batch, CH sequential steps ============
__global__ __launch_bounds__(256) void lif2_kernel(
        const float* __restrict__ a2, const float* __restrict__ W3,
        const float* __restrict__ b3, const float* __restrict__ noise,
        float* __restrict__ v2s, float* __restrict__ i2s,
        float* __restrict__ vls, float* __restrict__ ils,
        float* __restrict__ outmax, int c) {
    const int b = blockIdx.x;
    const int n = threadIdx.x;
    const int wid = n >> 6;
    const int lane = n & 63;
    __shared__ float part[4][NO];

    float w3r[NO];
    #pragma unroll
    for (int o = 0; o < NO; o++) w3r[o] = W3[o * N2 + n];

    float v2, i2;
    if (c == 0) { v2 = 0.f; i2 = 0.f; }
    else { v2 = v2s[(size_t)b * N2 + n]; i2 = i2s[(size_t)b * N2 + n]; }
    float vl = 0.f, il = 0.f, mx = -1e30f;
    if (n < NO && c > 0) { vl = vls[b*NO+n]; il = ils[b*NO+n]; mx = outmax[b*NO+n]; }

    for (int tl = 0; tl < CH; tl++) {
        float a2v = a2[((size_t)tl * BSZ + b) * N2 + n];
        float vd = v2 + DVM * (i2 - v2);
        bool z = (vd - VTH) > 0.f;
        v2 = z ? 0.f : vd;
        i2 = DIS * i2 + a2v;

        float cv[NO];
        #pragma unroll
        for (int o = 0; o < NO; o++) cv[o] = z ? w3r[o] : 0.f;
        #pragma unroll
        for (int s = 32; s > 0; s >>= 1)
            #pragma unroll
            for (int o = 0; o < NO; o++) cv[o] += __shfl_xor(cv[o], s, 64);
        if (lane == 0) {
            #pragma unroll
            for (int o = 0; o < NO; o++) part[wid][o] = cv[o];
        }
        __syncthreads();
        if (n < NO) {
            float a3 = part[0][n] + part[1][n] + part[2][n] + part[3][n] + b3[n];
            float vln = vl + DVM * (il - vl);
            il = DIS * il + a3;
            vl = vln;
            const int tg = c * CH + tl;
            float ov = vl + 0.001f * noise[((size_t)tg * BSZ + b) * NO + n];
            mx = fmaxf(mx, ov);
        }
        __syncthreads();
    }
    v2s[(size_t)b * N2 + n] = v2;
    i2s[(size_t)b * N2 + n] = i2;
    if (n < NO) { vls[b*NO+n] = vl; ils[b*NO+n] = il; outmax[b*NO+n] = mx; }
}

// ---------------- host ----------------
extern "C" void kernel_launch(void* const* d_in, const int* in_sizes, int n_in,
                              void* d_out, int out_size, void* d_ws, size_t ws_size,
                              hipStream_t stream) {
    const float* x     = (const float*)d_in[0];
    const float* W1    = (const float*)d_in[1];
    const float* b1    = (const float*)d_in[2];
    const float* W2    = (const float*)d_in[3];
    const float* b2    = (const float*)d_in[4];
    const float* W3    = (const float*)d_in[5];
    const float* b3    = (const float*)d_in[6];
    const float* noise = (const float*)d_in[7];
    float* out = (float*)d_out;

    char* ws = (char*)d_ws;
    float* inp1 = (float*)(ws + OFF_INP1);
    unsigned long long* z1 = (unsigned long long*)(ws + OFF_Z1);
    float* a2 = (float*)(ws + OFF_A2);
    float* v2 = (float*)(ws + OFF_V2);
    float* i2 = (float*)(ws + OFF_I2);
    float* vl = (float*)(ws + OFF_VL);
    float* il = (float*)(ws + OFF_IL);
    unsigned short* w2h = (unsigned short*)(ws + OFF_W2H);
    unsigned short* w2l = (unsigned short*)(ws + OFF_W2L);

    dim3 blk(256);
    prep_w2_kernel<<<dim3(N2 * N1 / 256), blk, 0, stream>>>(W2, w2h, w2l);
    gemm1_kernel<<<dim3(BSZ/64, N1/64), blk, 0, stream>>>(x, W1, b1, inp1);
    lif1_kernel<<<dim3(N1/256, BSZ), blk, 0, stream>>>(inp1, z1);
    for (int c = 0; c < NCHUNK; c++) {
        gemm2_mfma<<<dim3(CH * BSZ / 128), blk, 0, stream>>>(z1, w2h, w2l, b2, a2, c);
        lif2_kernel<<<dim3(BSZ), blk, 0, stream>>>(a2, W3, b3, noise, v2, i2, vl, il, out, c);
    }
}

// Round 3
// 1853.887 us; speedup vs baseline: 4.4770x; 2.2807x over previous
//
#include <hip/hip_runtime.h>

// ---------------- problem constants ----------------
#define BSZ   4096
#define NIN   3072
#define N1    1536
#define N2    256
#define NO    10
#define SEQ   128
#define CH    16            // timesteps per chunk
#define NCHUNK (SEQ/CH)

// dynamics constants
#define DVM  0.1f           // DT*TAU_MEM_INV
#define DIS  0.8f           // 1 - DT*TAU_SYN_INV
#define VTH  0.4f

// ---------------- workspace layout (bytes) ----------------
// [0, 67108864)           : inp1 (25 MB, dead after lif1) -> a2 (67 MB, per chunk) -> a3 (21 MB, after chunks)
// [67108864, 167772160)   : z1bits 100.7 MB
// [167772160, 171966464)  : v2
// [171966464, 176160768)  : i2
// [176160768, 192937984)  : z2bits 16.8 MB
// [192937984, 196083712)  : W2 frag (hi+lo interleaved) 3.1 MB
#define OFF_INP1 0
#define OFF_A2   0
#define OFF_A3   0
#define OFF_Z1   67108864
#define OFF_V2   167772160
#define OFF_I2   171966464
#define OFF_Z2   176160768
#define OFF_W2F  192937984

typedef short bf16x8 __attribute__((ext_vector_type(8)));
typedef float f32x4  __attribute__((ext_vector_type(4)));

__device__ __forceinline__ void gload_lds16(const unsigned short* g, unsigned short* l) {
    __builtin_amdgcn_global_load_lds(
        (const __attribute__((address_space(1))) unsigned int*)g,
        (__attribute__((address_space(3))) unsigned int*)l, 16, 0, 0);
}

// ============ GEMM1: inp1 = xf @ W1.T + b1  (4096x3072x1536, fp32) ============
__global__ __launch_bounds__(256) void gemm1_kernel(
        const float* __restrict__ xf, const float* __restrict__ W1,
        const float* __restrict__ b1, float* __restrict__ inp1) {
    __shared__ float As[32][68];   // [k][m]
    __shared__ float Bs[32][68];   // [k][n]
    const int m0 = blockIdx.x * 64;
    const int n0 = blockIdx.y * 64;
    const int tx = threadIdx.x;
    const int r0 = (tx >> 4) << 2;
    const int c0 = (tx & 15) << 2;
    const int sr = tx >> 2;
    const int sk = (tx & 3) << 3;
    const int g  = tx & 3;          // stagger group (kills 4-way write conflicts)

    float acc[4][4] = {};
    const float* aptr = xf + (size_t)(m0 + sr) * NIN + sk;
    const float* bptr = W1 + (size_t)(n0 + sr) * NIN + sk;

    for (int kk = 0; kk < NIN; kk += 32) {
        float4 av0 = *(const float4*)(aptr + kk);
        float4 av1 = *(const float4*)(aptr + kk + 4);
        float4 bv0 = *(const float4*)(bptr + kk);
        float4 bv1 = *(const float4*)(bptr + kk + 4);
        float a8[8] = {av0.x,av0.y,av0.z,av0.w,av1.x,av1.y,av1.z,av1.w};
        float b8[8] = {bv0.x,bv0.y,bv0.z,bv0.w,bv1.x,bv1.y,bv1.z,bv1.w};
        __syncthreads();
        #pragma unroll
        for (int j = 0; j < 8; j++) {
            const int jj = (j + g) & 7;
            As[sk + jj][sr] = a8[jj];
            Bs[sk + jj][sr] = b8[jj];
        }
        __syncthreads();
        #pragma unroll
        for (int k = 0; k < 32; k++) {
            float a[4], b[4];
            *(float4*)a = *(const float4*)&As[k][r0];
            *(float4*)b = *(const float4*)&Bs[k][c0];
            #pragma unroll
            for (int i = 0; i < 4; i++)
                #pragma unroll
                for (int j = 0; j < 4; j++)
                    acc[i][j] += a[i] * b[j];
        }
    }
    float4 bias = *(const float4*)&b1[n0 + c0];
    #pragma unroll
    for (int i = 0; i < 4; i++) {
        float4 o;
        o.x = acc[i][0] + bias.x; o.y = acc[i][1] + bias.y;
        o.z = acc[i][2] + bias.z; o.w = acc[i][3] + bias.w;
        *(float4*)&inp1[(size_t)(m0 + r0 + i) * N1 + n0 + c0] = o;
    }
}

// ============ LIF1: all 128 timesteps, spikes packed to bits ============
__global__ __launch_bounds__(256) void lif1_kernel(
        const float* __restrict__ inp1, unsigned long long* __restrict__ z1bits) {
    const int b = blockIdx.y;
    const int n = blockIdx.x * 256 + threadIdx.x;
    const int lane = threadIdx.x & 63;
    const int w = n >> 6;
    const float inp = inp1[(size_t)b * N1 + n];
    const size_t obase = (size_t)b * 24 + w;
    float v = 0.f, i = 0.f;
    for (int t = 0; t < SEQ; t++) {
        float vd = v + DVM * (i - v);
        bool z = (vd - VTH) > 0.f;
        unsigned long long m = __ballot(z);
        if (lane == 0) z1bits[(size_t)t * (BSZ * 24) + obase] = m;
        v = z ? 0.f : vd;
        i = DIS * i + inp;
    }
}

// ============ W2 prep: split hi/lo bf16 AND lay out in MFMA fragment order ============
// frag layout (shorts): chunk(w*2+nblk)[16384] ; within chunk:
//   ks*8192 + nt8*1024 + s*512 + lane*8 + j
// value = W2split[s][ n = (nblk*8+nt8)*16 + (lane&15) ][ k = w*64 + ks*32 + (lane>>4)*8 + j ]
__global__ __launch_bounds__(256) void prep_w2_kernel(
        const float* __restrict__ W2, unsigned short* __restrict__ frag) {
    const int idx = blockIdx.x * 256 + threadIdx.x;   // (w, ks, ntg, lane)
    const int lane = idx & 63;
    const int ntg  = (idx >> 6) & 15;
    const int ks   = (idx >> 10) & 1;
    const int w    = idx >> 11;                        // 0..23
    const int n = ntg * 16 + (lane & 15);
    const int k = w * 64 + ks * 32 + (lane >> 4) * 8;
    const int nblk = ntg >> 3, nt8 = ntg & 7;
    const size_t base = ((size_t)(w * 2 + nblk)) * 16384 + ks * 8192 + nt8 * 1024 + lane * 8;
    const float* src = W2 + (size_t)n * N1 + k;
    #pragma unroll
    for (int j = 0; j < 8; j++) {
        float x = src[j];
        unsigned u = __float_as_uint(x);
        unsigned rh = (u + 0x7FFFu + ((u >> 16) & 1u)) >> 16;     // RNE to bf16
        frag[base + j] = (unsigned short)rh;
        float r = x - __uint_as_float(rh << 16);
        unsigned u2 = __float_as_uint(r);
        frag[base + 512 + j] = (unsigned short)((u2 + 0x7FFFu + ((u2 >> 16) & 1u)) >> 16);
    }
}

// byte (8 spike bits) -> 8 bf16 {0.0, 1.0}
__device__ __forceinline__ bf16x8 expand8(unsigned int byte) {
    union { unsigned int u[4]; bf16x8 v; } r;
    #pragma unroll
    for (int p = 0; p < 4; p++) {
        unsigned int lo = ((byte >> (2*p)) & 1u) * 0x3F80u;
        unsigned int hi = ((byte >> (2*p+1)) & 1u) * 0x3F80u;
        r.u[p] = lo | (hi << 16);
    }
    return r.v;
}

// ============ GEMM2: a2 = z1 @ (W2hi+W2lo).T + b2 via MFMA, LDS double-buffered ============
// block 256 thr = 4 waves (2M x 2N); block tile 256M x 128N; wave 128M x 64N (mt=8, nt=4)
// BK=64 (one spike u64). B staged via global_load_lds from frag-ordered W2 -> conflict-free ds_read.
__global__ __launch_bounds__(256, 2) void gemm2_mfma(
        const unsigned long long* __restrict__ z1bits,
        const unsigned short* __restrict__ w2frag,
        const float* __restrict__ b2, float* __restrict__ a2, int c) {
    __shared__ unsigned short Bs[2][16384];    // 2 x 32 KB
    const int tx = threadIdx.x;
    const int wave = tx >> 6, lane = tx & 63;
    const int wm = wave >> 1, wn = wave & 1;
    const int ko = lane >> 4, ln = lane & 15;
    const int bm = blockIdx.x;                 // 0..255
    const int bn = blockIdx.y;                 // 0..1
    const int t_l = bm >> 4;
    const int b0 = (bm & 15) * 256 + wm * 128;
    const int t  = c * CH + t_l;

    f32x4 acc[8][4];
    #pragma unroll
    for (int mt = 0; mt < 8; mt++)
        #pragma unroll
        for (int nt = 0; nt < 4; nt++) acc[mt][nt] = (f32x4){0.f,0.f,0.f,0.f};

    const size_t zbase = ((size_t)t * BSZ + b0 + ln) * 24;

    // stage chunk (w, bn) into Bs[buf]: this wave's quarter = 8 x 1KB
    const unsigned short* sgbase = w2frag + (size_t)bn * 16384 + wave * 4096 + lane * 8;
    #define STAGE_B(w_, buf_) do {                                           \
        const unsigned short* s_ = sgbase + (size_t)(w_) * 32768;            \
        unsigned short* d_ = &Bs[buf_][wave * 4096];                         \
        _Pragma("unroll")                                                    \
        for (int j_ = 0; j_ < 8; j_++)                                       \
            gload_lds16(s_ + j_ * 512, d_ + j_ * 512);                       \
    } while (0)

    STAGE_B(0, 0);
    __syncthreads();                            // drains vmcnt + barrier

    for (int w = 0; w < 24; w++) {
        const int buf = w & 1;
        if (w < 23) STAGE_B(w + 1, buf ^ 1);
        // A: 8 spike words (rows b0 + mt*16 + ln)
        unsigned long long zw[8];
        #pragma unroll
        for (int mt = 0; mt < 8; mt++) zw[mt] = z1bits[zbase + mt * 384 + w];
        #pragma unroll
        for (int ks = 0; ks < 2; ks++) {
            bf16x8 af[8];
            #pragma unroll
            for (int mt = 0; mt < 8; mt++)
                af[mt] = expand8((unsigned int)(zw[mt] >> (ks * 32 + ko * 8)) & 0xFFu);
            #pragma unroll
            for (int nt = 0; nt < 4; nt++) {
                #pragma unroll
                for (int s = 0; s < 2; s++) {
                    bf16x8 bf = *(const bf16x8*)&Bs[buf][ks*8192 + (wn*4 + nt)*1024 + s*512 + lane*8];
                    #pragma unroll
                    for (int mt = 0; mt < 8; mt++)
                        acc[mt][nt] = __builtin_amdgcn_mfma_f32_16x16x32_bf16(af[mt], bf, acc[mt][nt], 0, 0, 0);
                }
            }
        }
        __syncthreads();                        // drains stage(w+1), orders buffer swap
    }
    // epilogue: C/D col=lane&15, row=(lane>>4)*4+r
    #pragma unroll
    for (int nt = 0; nt < 4; nt++) {
        const int o = bn * 128 + wn * 64 + nt * 16 + ln;
        const float bias = b2[o];
        #pragma unroll
        for (int mt = 0; mt < 8; mt++) {
            #pragma unroll
            for (int r = 0; r < 4; r++) {
                const int brow = b0 + mt * 16 + ko * 4 + r;
                a2[((size_t)t_l * BSZ + brow) * N2 + o] = acc[mt][nt][r] + bias;
            }
        }
    }
}

// ============ LIF2 spikes only: one thread per (b,n), CH sequential steps ============
__global__ __launch_bounds__(256) void lif2z_kernel(
        const float* __restrict__ a2, float* __restrict__ v2s, float* __restrict__ i2s,
        unsigned long long* __restrict__ z2bits, int c) {
    const int b = blockIdx.x;
    const int n = threadIdx.x;
    const int wid = n >> 6, lane = n & 63;
    float v2, i2;
    if (c == 0) { v2 = 0.f; i2 = 0.f; }
    else { v2 = v2s[(size_t)b * N2 + n]; i2 = i2s[(size_t)b * N2 + n]; }
    for (int tl = 0; tl < CH; tl++) {
        float a = a2[((size_t)tl * BSZ + b) * N2 + n];
        float vd = v2 + DVM * (i2 - v2);
        bool z = (vd - VTH) > 0.f;
        unsigned long long m = __ballot(z);
        if (lane == 0) z2bits[((size_t)(c * CH + tl) * BSZ + b) * 4 + wid] = m;
        v2 = z ? 0.f : vd;
        i2 = DIS * i2 + a;
    }
    v2s[(size_t)b * N2 + n] = v2;
    i2s[(size_t)b * N2 + n] = i2;
}

// ============ GEMM3: a3[t,b,:] = z2[t,b,:] @ W3.T + b3 (bit-dot, W3 via s_load) ============
__global__ __launch_bounds__(256) void gemm3_kernel(
        const unsigned long long* __restrict__ z2bits, const float* __restrict__ W3,
        const float* __restrict__ b3, float* __restrict__ a3) {
    const int idx = blockIdx.x * 256 + threadIdx.x;   // row = t*BSZ + b
    unsigned long long zw[4];
    #pragma unroll
    for (int g = 0; g < 4; g++) zw[g] = z2bits[(size_t)idx * 4 + g];
    float acc[NO];
    #pragma unroll
    for (int o = 0; o < NO; o++) acc[o] = b3[o];
    #pragma unroll
    for (int g = 0; g < 4; g++) {
        unsigned long long wg = zw[g];
        for (int kb = 0; kb < 64; kb++) {
            float bit = (float)((wg >> kb) & 1ull);
            #pragma unroll
            for (int o = 0; o < NO; o++)
                acc[o] = fmaf(bit, W3[o * N2 + g * 64 + kb], acc[o]);
        }
    }
    #pragma unroll
    for (int o = 0; o < NO; o++) a3[(size_t)idx * NO + o] = acc[o];
}

// ============ LI + max over time: one thread per (b,o) ============
__global__ __launch_bounds__(256) void li_kernel(
        const float* __restrict__ a3, const float* __restrict__ noise,
        float* __restrict__ out) {
    const int idx = blockIdx.x * 256 + threadIdx.x;   // b*NO + o
    if (idx >= BSZ * NO) return;
    float vl = 0.f, il = 0.f, mx = -1e30f;
    for (int t = 0; t < SEQ; t++) {
        float a = a3[(size_t)t * (BSZ * NO) + idx];
        float vn = vl + DVM * (il - vl);
        il = DIS * il + a;
        vl = vn;
        mx = fmaxf(mx, vl + 0.001f * noise[(size_t)t * (BSZ * NO) + idx]);
    }
    out[idx] = mx;
}

// ---------------- host ----------------
extern "C" void kernel_launch(void* const* d_in, const int* in_sizes, int n_in,
                              void* d_out, int out_size, void* d_ws, size_t ws_size,
                              hipStream_t stream) {
    const float* x     = (const float*)d_in[0];
    const float* W1    = (const float*)d_in[1];
    const float* b1    = (const float*)d_in[2];
    const float* W2    = (const float*)d_in[3];
    const float* b2    = (const float*)d_in[4];
    const float* W3    = (const float*)d_in[5];
    const float* b3    = (const float*)d_in[6];
    const float* noise = (const float*)d_in[7];
    float* out = (float*)d_out;

    char* ws = (char*)d_ws;
    float* inp1 = (float*)(ws + OFF_INP1);
    float* a2   = (float*)(ws + OFF_A2);
    float* a3   = (float*)(ws + OFF_A3);
    unsigned long long* z1 = (unsigned long long*)(ws + OFF_Z1);
    float* v2 = (float*)(ws + OFF_V2);
    float* i2 = (float*)(ws + OFF_I2);
    unsigned long long* z2 = (unsigned long long*)(ws + OFF_Z2);
    unsigned short* w2f = (unsigned short*)(ws + OFF_W2F);

    dim3 blk(256);
    prep_w2_kernel<<<dim3(192), blk, 0, stream>>>(W2, w2f);
    gemm1_kernel<<<dim3(BSZ/64, N1/64), blk, 0, stream>>>(x, W1, b1, inp1);
    lif1_kernel<<<dim3(N1/256, BSZ), blk, 0, stream>>>(inp1, z1);
    for (int c = 0; c < NCHUNK; c++) {
        gemm2_mfma<<<dim3(256, 2), blk, 0, stream>>>(z1, w2f, b2, a2, c);
        lif2z_kernel<<<dim3(BSZ), blk, 0, stream>>>(a2, v2, i2, z2, c);
    }
    gemm3_kernel<<<dim3(SEQ * BSZ / 256), blk, 0, stream>>>(z2, W3, b3, a3);
    li_kernel<<<dim3((BSZ * NO + 255) / 256), blk, 0, stream>>>(a3, noise, out);
}

// Round 4
// 1495.087 us; speedup vs baseline: 5.5514x; 1.2400x over previous
//
#include <hip/hip_runtime.h>

// ---------------- problem constants ----------------
#define BSZ   4096
#define NIN   3072
#define N1    1536
#define N2    256
#define NO    10
#define SEQ   128
#define CH    16            // timesteps per chunk
#define NCHUNK (SEQ/CH)

// dynamics constants
#define DVM  0.1f           // DT*TAU_MEM_INV
#define DIS  0.8f           // 1 - DT*TAU_SYN_INV
#define VTH  0.4f

// ---------------- workspace layout (bytes) ----------------
// [0, 67108864)        : inp1 (25MB) -> a2 (67MB per chunk) -> a3 (21MB)
// [67108864, ...)      : xfrag (75.5MB, dead after gemm1)  UNION  z1bits (100.7MB)
// [167772160, ...)     : w1frag (28.3MB, dead after gemm1) UNION  v2+i2+z2 (25.2MB)
// [196083712, ...)     : w2frag 3.1MB ; end 199229440
#define OFF_INP1 0
#define OFF_A2   0
#define OFF_A3   0
#define OFF_XF   67108864
#define OFF_Z1   67108864
#define OFF_W1F  167772160
#define OFF_V2   167772160
#define OFF_I2   171966464
#define OFF_Z2   176160768
#define OFF_W2F  196083712

typedef short bf16x8 __attribute__((ext_vector_type(8)));
typedef float f32x4  __attribute__((ext_vector_type(4)));

__device__ __forceinline__ void gload_lds16(const unsigned short* g, unsigned short* l) {
    __builtin_amdgcn_global_load_lds(
        (const __attribute__((address_space(1))) unsigned int*)g,
        (__attribute__((address_space(3))) unsigned int*)l, 16, 0, 0);
}

__device__ __forceinline__ unsigned short rne_bf16(float x) {
    unsigned u = __float_as_uint(x);
    return (unsigned short)((u + 0x7FFFu + ((u >> 16) & 1u)) >> 16);
}
__device__ __forceinline__ float bf2f(unsigned short h) {
    return __uint_as_float(((unsigned)h) << 16);
}

// ============ prep_x: 3-digit bf16 split of x, MFMA-fragment order ============
// chunk(ks 0..95, m16 0..255): [dig 0..2][lane 0..63][8 shorts]
// value = dig_d( x[m16*16 + (lane&15)][ks*32 + (lane>>4)*8 + j] )
__global__ __launch_bounds__(256) void prep_x_kernel(
        const float* __restrict__ x, unsigned short* __restrict__ xf) {
    const int idx = blockIdx.x * 256 + threadIdx.x;
    const int lane = idx & 63;
    const int m16 = (idx >> 6) & 255;
    const int ks  = idx >> 14;                 // 0..95
    const int row = m16 * 16 + (lane & 15);
    const int k0  = ks * 32 + (lane >> 4) * 8;
    const float* src = x + (size_t)row * NIN + k0;
    union { unsigned short u[8]; bf16x8 v; } h, m, l;
    #pragma unroll
    for (int j = 0; j < 8; j++) {
        float v = src[j];
        h.u[j] = rne_bf16(v);
        float r1 = v - bf2f(h.u[j]);
        m.u[j] = rne_bf16(r1);
        float r2 = r1 - bf2f(m.u[j]);
        l.u[j] = rne_bf16(r2);
    }
    unsigned short* dst = xf + ((size_t)(ks * 256 + m16) * 3) * 512 + lane * 8;
    *(bf16x8*)(dst)        = h.v;
    *(bf16x8*)(dst + 512)  = m.v;
    *(bf16x8*)(dst + 1024) = l.v;
}

// ============ prep_w1: 3-digit split of W1, fragment order for LDS staging ============
// chunk(ks 0..95, ntile 0..11) = 12288 shorts: [nt8 0..7][dig][lane][8]
__global__ __launch_bounds__(256) void prep_w1_kernel(
        const float* __restrict__ W1, unsigned short* __restrict__ wf) {
    const int idx = blockIdx.x * 256 + threadIdx.x;
    const int ks  = idx / 6144;                // 0..95
    const int rem = idx % 6144;
    const int n16 = rem >> 6;                  // 0..95
    const int lane = rem & 63;
    const int row = n16 * 16 + (lane & 15);
    const int k0  = ks * 32 + (lane >> 4) * 8;
    const float* src = W1 + (size_t)row * NIN + k0;
    union { unsigned short u[8]; bf16x8 v; } h, m, l;
    #pragma unroll
    for (int j = 0; j < 8; j++) {
        float v = src[j];
        h.u[j] = rne_bf16(v);
        float r1 = v - bf2f(h.u[j]);
        m.u[j] = rne_bf16(r1);
        float r2 = r1 - bf2f(m.u[j]);
        l.u[j] = rne_bf16(r2);
    }
    unsigned short* dst = wf + ((size_t)ks * 12 + (n16 >> 3)) * 12288
                             + (n16 & 7) * 1536 + lane * 8;
    *(bf16x8*)(dst)        = h.v;
    *(bf16x8*)(dst + 512)  = m.v;
    *(bf16x8*)(dst + 1024) = l.v;
}

// ============ GEMM1 via MFMA: inp1 = x @ W1.T + b1, 6-product digit split ============
// block 256 thr = 4 waves (2m x 2n); tile 128M x 128N; wave 64x64 (mt=4, nt=4); BK=32
// products kept: hh, mh, lh, hm, mm, hl  (dropped ~2^-27 terms)
__global__ __launch_bounds__(256, 2) void gemm1_mfma(
        const unsigned short* __restrict__ xf, const unsigned short* __restrict__ w1f,
        const float* __restrict__ b1, float* __restrict__ inp1) {
    __shared__ unsigned short Bs[2][12288];    // 2 x 24 KB
    const int tx = threadIdx.x;
    const int wave = tx >> 6, lane = tx & 63;
    const int wm = wave >> 1, wn = wave & 1;
    const int ln = lane & 15, ko = lane >> 4;
    const int bid = blockIdx.x;                // 384 blocks
    const int wg = (bid & 7) * 48 + (bid >> 3);   // XCD-chunked swizzle (384%8==0)
    const int mtile = wg / 12, ntile = wg % 12;
    const int m16b = mtile * 8 + wm * 4;

    f32x4 acc[4][4];
    #pragma unroll
    for (int mt = 0; mt < 4; mt++)
        #pragma unroll
        for (int nt = 0; nt < 4; nt++) acc[mt][nt] = (f32x4){0.f,0.f,0.f,0.f};

    const unsigned short* xfr = xf + lane * 8;

#define ALOAD(A_, ks_) do {                                                   \
    _Pragma("unroll")                                                         \
    for (int mt_ = 0; mt_ < 4; mt_++)                                         \
        _Pragma("unroll")                                                     \
        for (int d_ = 0; d_ < 3; d_++)                                        \
            A_[mt_][d_] = *(const bf16x8*)(xfr +                              \
                (((size_t)(ks_) * 256 + m16b + mt_) * 3 + d_) * 512);         \
} while (0)

#define STAGE1(ks_, buf_) do {                                                \
    const unsigned short* s_ = w1f + ((size_t)(ks_) * 12 + ntile) * 12288     \
                                   + wave * 3072 + lane * 8;                  \
    unsigned short* d_ = &Bs[buf_][wave * 3072];                              \
    _Pragma("unroll")                                                         \
    for (int j_ = 0; j_ < 6; j_++)                                            \
        gload_lds16(s_ + j_ * 512, d_ + j_ * 512);                            \
} while (0)

#define COMPUTE(A_, buf_) do {                                                \
    _Pragma("unroll")                                                         \
    for (int nt_ = 0; nt_ < 4; nt_++) {                                       \
        const unsigned short* bp_ = &Bs[buf_][(wn * 4 + nt_) * 1536 + lane * 8]; \
        bf16x8 bh_ = *(const bf16x8*)(bp_);                                   \
        bf16x8 bm_ = *(const bf16x8*)(bp_ + 512);                             \
        bf16x8 bl_ = *(const bf16x8*)(bp_ + 1024);                            \
        _Pragma("unroll")                                                     \
        for (int mt_ = 0; mt_ < 4; mt_++) {                                   \
            acc[mt_][nt_] = __builtin_amdgcn_mfma_f32_16x16x32_bf16(A_[mt_][0], bh_, acc[mt_][nt_], 0, 0, 0); \
            acc[mt_][nt_] = __builtin_amdgcn_mfma_f32_16x16x32_bf16(A_[mt_][1], bh_, acc[mt_][nt_], 0, 0, 0); \
            acc[mt_][nt_] = __builtin_amdgcn_mfma_f32_16x16x32_bf16(A_[mt_][2], bh_, acc[mt_][nt_], 0, 0, 0); \
            acc[mt_][nt_] = __builtin_amdgcn_mfma_f32_16x16x32_bf16(A_[mt_][0], bm_, acc[mt_][nt_], 0, 0, 0); \
            acc[mt_][nt_] = __builtin_amdgcn_mfma_f32_16x16x32_bf16(A_[mt_][1], bm_, acc[mt_][nt_], 0, 0, 0); \
            acc[mt_][nt_] = __builtin_amdgcn_mfma_f32_16x16x32_bf16(A_[mt_][0], bl_, acc[mt_][nt_], 0, 0, 0); \
        }                                                                     \
    }                                                                         \
} while (0)

    bf16x8 aA[4][3], aB[4][3];
    ALOAD(aA, 0);
    STAGE1(0, 0);
    __syncthreads();

    for (int ks = 0; ks < 96; ks += 2) {
        STAGE1(ks + 1, 1);
        ALOAD(aB, ks + 1);
        COMPUTE(aA, 0);
        __syncthreads();
        if (ks + 2 < 96) {
            STAGE1(ks + 2, 0);
            ALOAD(aA, ks + 2);
        }
        COMPUTE(aB, 1);
        __syncthreads();
    }

    // epilogue: C/D col=lane&15, row=(lane>>4)*4+r
    #pragma unroll
    for (int nt = 0; nt < 4; nt++) {
        const int n = ntile * 128 + wn * 64 + nt * 16 + ln;
        const float bias = b1[n];
        #pragma unroll
        for (int mt = 0; mt < 4; mt++) {
            #pragma unroll
            for (int r = 0; r < 4; r++) {
                const int m = mtile * 128 + wm * 64 + mt * 16 + ko * 4 + r;
                inp1[(size_t)m * N1 + n] = acc[mt][nt][r] + bias;
            }
        }
    }
#undef ALOAD
#undef STAGE1
#undef COMPUTE
}

// ============ LIF1: all 128 timesteps, spikes packed to bits ============
__global__ __launch_bounds__(256) void lif1_kernel(
        const float* __restrict__ inp1, unsigned long long* __restrict__ z1bits) {
    const int b = blockIdx.y;
    const int n = blockIdx.x * 256 + threadIdx.x;
    const int lane = threadIdx.x & 63;
    const int w = n >> 6;
    const float inp = inp1[(size_t)b * N1 + n];
    const size_t obase = (size_t)b * 24 + w;
    float v = 0.f, i = 0.f;
    for (int t = 0; t < SEQ; t++) {
        float vd = v + DVM * (i - v);
        bool z = (vd - VTH) > 0.f;
        unsigned long long m = __ballot(z);
        if (lane == 0) z1bits[(size_t)t * (BSZ * 24) + obase] = m;
        v = z ? 0.f : vd;
        i = DIS * i + inp;
    }
}

// ============ W2 prep: split hi/lo bf16 in MFMA fragment order ============
__global__ __launch_bounds__(256) void prep_w2_kernel(
        const float* __restrict__ W2, unsigned short* __restrict__ frag) {
    const int idx = blockIdx.x * 256 + threadIdx.x;
    const int lane = idx & 63;
    const int ntg  = (idx >> 6) & 15;
    const int ks   = (idx >> 10) & 1;
    const int w    = idx >> 11;
    const int n = ntg * 16 + (lane & 15);
    const int k = w * 64 + ks * 32 + (lane >> 4) * 8;
    const int nblk = ntg >> 3, nt8 = ntg & 7;
    const size_t base = ((size_t)(w * 2 + nblk)) * 16384 + ks * 8192 + nt8 * 1024 + lane * 8;
    const float* src = W2 + (size_t)n * N1 + k;
    #pragma unroll
    for (int j = 0; j < 8; j++) {
        float x = src[j];
        unsigned short h = rne_bf16(x);
        frag[base + j] = h;
        float r = x - bf2f(h);
        frag[base + 512 + j] = rne_bf16(r);
    }
}

// byte (8 spike bits) -> 8 bf16 {0.0, 1.0}
__device__ __forceinline__ bf16x8 expand8(unsigned int byte) {
    union { unsigned int u[4]; bf16x8 v; } r;
    #pragma unroll
    for (int p = 0; p < 4; p++) {
        unsigned int lo = ((byte >> (2*p)) & 1u) * 0x3F80u;
        unsigned int hi = ((byte >> (2*p+1)) & 1u) * 0x3F80u;
        r.u[p] = lo | (hi << 16);
    }
    return r.v;
}

// ============ GEMM2: a2 = z1 @ (W2hi+W2lo).T + b2 via MFMA ============
__global__ __launch_bounds__(256, 2) void gemm2_mfma(
        const unsigned long long* __restrict__ z1bits,
        const unsigned short* __restrict__ w2frag,
        const float* __restrict__ b2, float* __restrict__ a2, int c) {
    __shared__ unsigned short Bs[2][16384];
    const int tx = threadIdx.x;
    const int wave = tx >> 6, lane = tx & 63;
    const int wm = wave >> 1, wn = wave & 1;
    const int ko = lane >> 4, ln = lane & 15;
    const int bm = blockIdx.x;
    const int bn = blockIdx.y;
    const int t_l = bm >> 4;
    const int b0 = (bm & 15) * 256 + wm * 128;
    const int t  = c * CH + t_l;

    f32x4 acc[8][4];
    #pragma unroll
    for (int mt = 0; mt < 8; mt++)
        #pragma unroll
        for (int nt = 0; nt < 4; nt++) acc[mt][nt] = (f32x4){0.f,0.f,0.f,0.f};

    const size_t zbase = ((size_t)t * BSZ + b0 + ln) * 24;
    const unsigned short* sgbase = w2frag + (size_t)bn * 16384 + wave * 4096 + lane * 8;
    #define STAGE_B(w_, buf_) do {                                           \
        const unsigned short* s_ = sgbase + (size_t)(w_) * 32768;            \
        unsigned short* d_ = &Bs[buf_][wave * 4096];                         \
        _Pragma("unroll")                                                    \
        for (int j_ = 0; j_ < 8; j_++)                                       \
            gload_lds16(s_ + j_ * 512, d_ + j_ * 512);                       \
    } while (0)

    STAGE_B(0, 0);
    __syncthreads();

    for (int w = 0; w < 24; w++) {
        const int buf = w & 1;
        if (w < 23) STAGE_B(w + 1, buf ^ 1);
        unsigned long long zw[8];
        #pragma unroll
        for (int mt = 0; mt < 8; mt++) zw[mt] = z1bits[zbase + mt * 384 + w];
        #pragma unroll
        for (int ks = 0; ks < 2; ks++) {
            bf16x8 af[8];
            #pragma unroll
            for (int mt = 0; mt < 8; mt++)
                af[mt] = expand8((unsigned int)(zw[mt] >> (ks * 32 + ko * 8)) & 0xFFu);
            #pragma unroll
            for (int nt = 0; nt < 4; nt++) {
                #pragma unroll
                for (int s = 0; s < 2; s++) {
                    bf16x8 bf = *(const bf16x8*)&Bs[buf][ks*8192 + (wn*4 + nt)*1024 + s*512 + lane*8];
                    #pragma unroll
                    for (int mt = 0; mt < 8; mt++)
                        acc[mt][nt] = __builtin_amdgcn_mfma_f32_16x16x32_bf16(af[mt], bf, acc[mt][nt], 0, 0, 0);
                }
            }
        }
        __syncthreads();
    }
    #pragma unroll
    for (int nt = 0; nt < 4; nt++) {
        const int o = bn * 128 + wn * 64 + nt * 16 + ln;
        const float bias = b2[o];
        #pragma unroll
        for (int mt = 0; mt < 8; mt++) {
            #pragma unroll
            for (int r = 0; r < 4; r++) {
                const int brow = b0 + mt * 16 + ko * 4 + r;
                a2[((size_t)t_l * BSZ + brow) * N2 + o] = acc[mt][nt][r] + bias;
            }
        }
    }
    #undef STAGE_B
}

// ============ LIF2 spikes only ============
__global__ __launch_bounds__(256) void lif2z_kernel(
        const float* __restrict__ a2, float* __restrict__ v2s, float* __restrict__ i2s,
        unsigned long long* __restrict__ z2bits, int c) {
    const int b = blockIdx.x;
    const int n = threadIdx.x;
    const int wid = n >> 6, lane = n & 63;
    float v2, i2;
    if (c == 0) { v2 = 0.f; i2 = 0.f; }
    else { v2 = v2s[(size_t)b * N2 + n]; i2 = i2s[(size_t)b * N2 + n]; }
    for (int tl = 0; tl < CH; tl++) {
        float a = a2[((size_t)tl * BSZ + b) * N2 + n];
        float vd = v2 + DVM * (i2 - v2);
        bool z = (vd - VTH) > 0.f;
        unsigned long long m = __ballot(z);
        if (lane == 0) z2bits[((size_t)(c * CH + tl) * BSZ + b) * 4 + wid] = m;
        v2 = z ? 0.f : vd;
        i2 = DIS * i2 + a;
    }
    v2s[(size_t)b * N2 + n] = v2;
    i2s[(size_t)b * N2 + n] = i2;
}

// ============ GEMM3: a3 = z2 @ W3.T + b3 (bit-dot) ============
__global__ __launch_bounds__(256) void gemm3_kernel(
        const unsigned long long* __restrict__ z2bits, const float* __restrict__ W3,
        const float* __restrict__ b3, float* __restrict__ a3) {
    const int idx = blockIdx.x * 256 + threadIdx.x;
    unsigned long long zw[4];
    #pragma unroll
    for (int g = 0; g < 4; g++) zw[g] = z2bits[(size_t)idx * 4 + g];
    float acc[NO];
    #pragma unroll
    for (int o = 0; o < NO; o++) acc[o] = b3[o];
    #pragma unroll
    for (int g = 0; g < 4; g++) {
        unsigned long long wg = zw[g];
        for (int kb = 0; kb < 64; kb++) {
            float bit = (float)((wg >> kb) & 1ull);
            #pragma unroll
            for (int o = 0; o < NO; o++)
                acc[o] = fmaf(bit, W3[o * N2 + g * 64 + kb], acc[o]);
        }
    }
    #pragma unroll
    for (int o = 0; o < NO; o++) a3[(size_t)idx * NO + o] = acc[o];
}

// ============ LI + max over time ============
__global__ __launch_bounds__(256) void li_kernel(
        const float* __restrict__ a3, const float* __restrict__ noise,
        float* __restrict__ out) {
    const int idx = blockIdx.x * 256 + threadIdx.x;
    if (idx >= BSZ * NO) return;
    float vl = 0.f, il = 0.f, mx = -1e30f;
    for (int t = 0; t < SEQ; t++) {
        float a = a3[(size_t)t * (BSZ * NO) + idx];
        float vn = vl + DVM * (il - vl);
        il = DIS * il + a;
        vl = vn;
        mx = fmaxf(mx, vl + 0.001f * noise[(size_t)t * (BSZ * NO) + idx]);
    }
    out[idx] = mx;
}

// ---------------- host ----------------
extern "C" void kernel_launch(void* const* d_in, const int* in_sizes, int n_in,
                              void* d_out, int out_size, void* d_ws, size_t ws_size,
                              hipStream_t stream) {
    const float* x     = (const float*)d_in[0];
    const float* W1    = (const float*)d_in[1];
    const float* b1    = (const float*)d_in[2];
    const float* W2    = (const float*)d_in[3];
    const float* b2    = (const float*)d_in[4];
    const float* W3    = (const float*)d_in[5];
    const float* b3    = (const float*)d_in[6];
    const float* noise = (const float*)d_in[7];
    float* out = (float*)d_out;

    char* ws = (char*)d_ws;
    float* inp1 = (float*)(ws + OFF_INP1);
    float* a2   = (float*)(ws + OFF_A2);
    float* a3   = (float*)(ws + OFF_A3);
    unsigned short* xf  = (unsigned short*)(ws + OFF_XF);
    unsigned short* w1f = (unsigned short*)(ws + OFF_W1F);
    unsigned long long* z1 = (unsigned long long*)(ws + OFF_Z1);
    float* v2 = (float*)(ws + OFF_V2);
    float* i2 = (float*)(ws + OFF_I2);
    unsigned long long* z2 = (unsigned long long*)(ws + OFF_Z2);
    unsigned short* w2f = (unsigned short*)(ws + OFF_W2F);

    dim3 blk(256);
    prep_x_kernel<<<dim3(6144), blk, 0, stream>>>(x, xf);
    prep_w1_kernel<<<dim3(2304), blk, 0, stream>>>(W1, w1f);
    prep_w2_kernel<<<dim3(192), blk, 0, stream>>>(W2, w2f);
    gemm1_mfma<<<dim3(384), blk, 0, stream>>>(xf, w1f, b1, inp1);
    lif1_kernel<<<dim3(N1/256, BSZ), blk, 0, stream>>>(inp1, z1);   // z1 overlays xf (dead)
    for (int c = 0; c < NCHUNK; c++) {
        gemm2_mfma<<<dim3(256, 2), blk, 0, stream>>>(z1, w2f, b2, a2, c);
        lif2z_kernel<<<dim3(BSZ), blk, 0, stream>>>(a2, v2, i2, z2, c);  // v2/i2/z2 overlay w1f (dead)
    }
    gemm3_kernel<<<dim3(SEQ * BSZ / 256), blk, 0, stream>>>(z2, W3, b3, a3);
    li_kernel<<<dim3((BSZ * NO + 255) / 256), blk, 0, stream>>>(a3, noise, out);
}

// Round 5
// 1431.108 us; speedup vs baseline: 5.7996x; 1.0447x over previous
//
#include <hip/hip_runtime.h>

// ---------------- problem constants ----------------
#define BSZ   4096
#define NIN   3072
#define N1    1536
#define N2    256
#define NO    10
#define SEQ   128
#define CH    16            // timesteps per chunk
#define NCHUNK (SEQ/CH)

// dynamics constants
#define DVM  0.1f           // DT*TAU_MEM_INV
#define DIS  0.8f           // 1 - DT*TAU_SYN_INV
#define VTH  0.4f

// ---------------- workspace layout (bytes) ----------------
// [0, 67108864)        : inp1 (25MB) -> a2 (67MB per chunk) -> a3 (21MB)
// [67108864, ...)      : xfrag (75.5MB, dead after gemm1)  UNION  z1bits (100.7MB)
// [167772160, ...)     : w1frag (28.3MB, dead after gemm1) UNION  v2+i2+z2 (25.2MB)
// [196083712, ...)     : w2frag 3.1MB ; end 199229440
#define OFF_INP1 0
#define OFF_A2   0
#define OFF_A3   0
#define OFF_XF   67108864
#define OFF_Z1   67108864
#define OFF_W1F  167772160
#define OFF_V2   167772160
#define OFF_I2   171966464
#define OFF_Z2   176160768
#define OFF_W2F  196083712

typedef short bf16x8 __attribute__((ext_vector_type(8)));
typedef float f32x4  __attribute__((ext_vector_type(4)));

__device__ __forceinline__ void gload_lds16(const unsigned short* g, unsigned short* l) {
    __builtin_amdgcn_global_load_lds(
        (const __attribute__((address_space(1))) unsigned int*)g,
        (__attribute__((address_space(3))) unsigned int*)l, 16, 0, 0);
}

__device__ __forceinline__ unsigned short rne_bf16(float x) {
    unsigned u = __float_as_uint(x);
    return (unsigned short)((u + 0x7FFFu + ((u >> 16) & 1u)) >> 16);
}
__device__ __forceinline__ float bf2f(unsigned short h) {
    return __uint_as_float(((unsigned)h) << 16);
}

// ============ prep_x: 3-digit bf16 split of x, MFMA-fragment order ============
__global__ __launch_bounds__(256) void prep_x_kernel(
        const float* __restrict__ x, unsigned short* __restrict__ xf) {
    const int idx = blockIdx.x * 256 + threadIdx.x;
    const int lane = idx & 63;
    const int m16 = (idx >> 6) & 255;
    const int ks  = idx >> 14;                 // 0..95
    const int row = m16 * 16 + (lane & 15);
    const int k0  = ks * 32 + (lane >> 4) * 8;
    const float* src = x + (size_t)row * NIN + k0;
    union { unsigned short u[8]; bf16x8 v; } h, m, l;
    #pragma unroll
    for (int j = 0; j < 8; j++) {
        float v = src[j];
        h.u[j] = rne_bf16(v);
        float r1 = v - bf2f(h.u[j]);
        m.u[j] = rne_bf16(r1);
        float r2 = r1 - bf2f(m.u[j]);
        l.u[j] = rne_bf16(r2);
    }
    unsigned short* dst = xf + ((size_t)(ks * 256 + m16) * 3) * 512 + lane * 8;
    *(bf16x8*)(dst)        = h.v;
    *(bf16x8*)(dst + 512)  = m.v;
    *(bf16x8*)(dst + 1024) = l.v;
}

// ============ prep_w1: 3-digit split of W1, fragment order for LDS staging ============
__global__ __launch_bounds__(256) void prep_w1_kernel(
        const float* __restrict__ W1, unsigned short* __restrict__ wf) {
    const int idx = blockIdx.x * 256 + threadIdx.x;
    const int ks  = idx / 6144;                // 0..95
    const int rem = idx % 6144;
    const int n16 = rem >> 6;                  // 0..95
    const int lane = rem & 63;
    const int row = n16 * 16 + (lane & 15);
    const int k0  = ks * 32 + (lane >> 4) * 8;
    const float* src = W1 + (size_t)row * NIN + k0;
    union { unsigned short u[8]; bf16x8 v; } h, m, l;
    #pragma unroll
    for (int j = 0; j < 8; j++) {
        float v = src[j];
        h.u[j] = rne_bf16(v);
        float r1 = v - bf2f(h.u[j]);
        m.u[j] = rne_bf16(r1);
        float r2 = r1 - bf2f(m.u[j]);
        l.u[j] = rne_bf16(r2);
    }
    unsigned short* dst = wf + ((size_t)ks * 12 + (n16 >> 3)) * 12288
                             + (n16 & 7) * 1536 + lane * 8;
    *(bf16x8*)(dst)        = h.v;
    *(bf16x8*)(dst + 512)  = m.v;
    *(bf16x8*)(dst + 1024) = l.v;
}

// ============ GEMM1 via MFMA: inp1 = x @ W1.T + b1, 6-product digit split ============
__global__ __launch_bounds__(256, 2) void gemm1_mfma(
        const unsigned short* __restrict__ xf, const unsigned short* __restrict__ w1f,
        const float* __restrict__ b1, float* __restrict__ inp1) {
    __shared__ unsigned short Bs[2][12288];    // 2 x 24 KB
    const int tx = threadIdx.x;
    const int wave = tx >> 6, lane = tx & 63;
    const int wm = wave >> 1, wn = wave & 1;
    const int ln = lane & 15, ko = lane >> 4;
    const int bid = blockIdx.x;                // 384 blocks
    const int wg = (bid & 7) * 48 + (bid >> 3);   // XCD-chunked swizzle (384%8==0)
    const int mtile = wg / 12, ntile = wg % 12;
    const int m16b = mtile * 8 + wm * 4;

    f32x4 acc[4][4];
    #pragma unroll
    for (int mt = 0; mt < 4; mt++)
        #pragma unroll
        for (int nt = 0; nt < 4; nt++) acc[mt][nt] = (f32x4){0.f,0.f,0.f,0.f};

    const unsigned short* xfr = xf + lane * 8;

#define ALOAD(A_, ks_) do {                                                   \
    _Pragma("unroll")                                                         \
    for (int mt_ = 0; mt_ < 4; mt_++)                                         \
        _Pragma("unroll")                                                     \
        for (int d_ = 0; d_ < 3; d_++)                                        \
            A_[mt_][d_] = *(const bf16x8*)(xfr +                              \
                (((size_t)(ks_) * 256 + m16b + mt_) * 3 + d_) * 512);         \
} while (0)

#define STAGE1(ks_, buf_) do {                                                \
    const unsigned short* s_ = w1f + ((size_t)(ks_) * 12 + ntile) * 12288     \
                                   + wave * 3072 + lane * 8;                  \
    unsigned short* d_ = &Bs[buf_][wave * 3072];                              \
    _Pragma("unroll")                                                         \
    for (int j_ = 0; j_ < 6; j_++)                                            \
        gload_lds16(s_ + j_ * 512, d_ + j_ * 512);                            \
} while (0)

#define COMPUTE(A_, buf_) do {                                                \
    _Pragma("unroll")                                                         \
    for (int nt_ = 0; nt_ < 4; nt_++) {                                       \
        const unsigned short* bp_ = &Bs[buf_][(wn * 4 + nt_) * 1536 + lane * 8]; \
        bf16x8 bh_ = *(const bf16x8*)(bp_);                                   \
        bf16x8 bm_ = *(const bf16x8*)(bp_ + 512);                             \
        bf16x8 bl_ = *(const bf16x8*)(bp_ + 1024);                            \
        _Pragma("unroll")                                                     \
        for (int mt_ = 0; mt_ < 4; mt_++) {                                   \
            acc[mt_][nt_] = __builtin_amdgcn_mfma_f32_16x16x32_bf16(A_[mt_][0], bh_, acc[mt_][nt_], 0, 0, 0); \
            acc[mt_][nt_] = __builtin_amdgcn_mfma_f32_16x16x32_bf16(A_[mt_][1], bh_, acc[mt_][nt_], 0, 0, 0); \
            acc[mt_][nt_] = __builtin_amdgcn_mfma_f32_16x16x32_bf16(A_[mt_][2], bh_, acc[mt_][nt_], 0, 0, 0); \
            acc[mt_][nt_] = __builtin_amdgcn_mfma_f32_16x16x32_bf16(A_[mt_][0], bm_, acc[mt_][nt_], 0, 0, 0); \
            acc[mt_][nt_] = __builtin_amdgcn_mfma_f32_16x16x32_bf16(A_[mt_][1], bm_, acc[mt_][nt_], 0, 0, 0); \
            acc[mt_][nt_] = __builtin_amdgcn_mfma_f32_16x16x32_bf16(A_[mt_][0], bl_, acc[mt_][nt_], 0, 0, 0); \
        }                                                                     \
    }                                                                         \
} while (0)

    bf16x8 aA[4][3], aB[4][3];
    ALOAD(aA, 0);
    STAGE1(0, 0);
    __syncthreads();

    for (int ks = 0; ks < 96; ks += 2) {
        STAGE1(ks + 1, 1);
        ALOAD(aB, ks + 1);
        COMPUTE(aA, 0);
        __syncthreads();
        if (ks + 2 < 96) {
            STAGE1(ks + 2, 0);
            ALOAD(aA, ks + 2);
        }
        COMPUTE(aB, 1);
        __syncthreads();
    }

    // epilogue: C/D col=lane&15, row=(lane>>4)*4+r
    #pragma unroll
    for (int nt = 0; nt < 4; nt++) {
        const int n = ntile * 128 + wn * 64 + nt * 16 + ln;
        const float bias = b1[n];
        #pragma unroll
        for (int mt = 0; mt < 4; mt++) {
            #pragma unroll
            for (int r = 0; r < 4; r++) {
                const int m = mtile * 128 + wm * 64 + mt * 16 + ko * 4 + r;
                inp1[(size_t)m * N1 + n] = acc[mt][nt][r] + bias;
            }
        }
    }
#undef ALOAD
#undef STAGE1
#undef COMPUTE
}

// ============ LIF1: 128 timesteps, spikes packed; NEW layout z1a[b][w][t] ============
// Per t: ballot mask captured by lane (t&63) via register selects (no exec dance,
// no per-t store). One coalesced 512B store per wave per 64-t segment.
__global__ __launch_bounds__(256) void lif1_kernel(
        const float* __restrict__ inp1, unsigned long long* __restrict__ z1a) {
    const int b = blockIdx.y;
    const int n = blockIdx.x * 256 + threadIdx.x;
    const int lane = threadIdx.x & 63;
    const int w = n >> 6;                      // word index 0..23
    const float inp = inp1[(size_t)b * N1 + n];
    unsigned long long* obase = z1a + (size_t)b * 3072 + (size_t)w * 128;
    float v = 0.f, i = 0.f;
    #pragma unroll 1
    for (int seg = 0; seg < 2; seg++) {
        unsigned int plo = 0, phi = 0;
        #pragma unroll
        for (int tt = 0; tt < 64; tt++) {
            float vd = v + DVM * (i - v);
            bool z = (vd - VTH) > 0.f;
            unsigned long long m = __ballot(z);
            if (lane == tt) { plo = (unsigned int)m; phi = (unsigned int)(m >> 32); }
            v = z ? 0.f : vd;
            i = DIS * i + inp;
        }
        obase[seg * 64 + lane] = ((unsigned long long)phi << 32) | plo;
    }
}

// ============ W2 prep: split hi/lo bf16 in MFMA fragment order ============
__global__ __launch_bounds__(256) void prep_w2_kernel(
        const float* __restrict__ W2, unsigned short* __restrict__ frag) {
    const int idx = blockIdx.x * 256 + threadIdx.x;
    const int lane = idx & 63;
    const int ntg  = (idx >> 6) & 15;
    const int ks   = (idx >> 10) & 1;
    const int w    = idx >> 11;
    const int n = ntg * 16 + (lane & 15);
    const int k = w * 64 + ks * 32 + (lane >> 4) * 8;
    const int nblk = ntg >> 3, nt8 = ntg & 7;
    const size_t base = ((size_t)(w * 2 + nblk)) * 16384 + ks * 8192 + nt8 * 1024 + lane * 8;
    const float* src = W2 + (size_t)n * N1 + k;
    #pragma unroll
    for (int j = 0; j < 8; j++) {
        float x = src[j];
        unsigned short h = rne_bf16(x);
        frag[base + j] = h;
        float r = x - bf2f(h);
        frag[base + 512 + j] = rne_bf16(r);
    }
}

// byte (8 spike bits) -> 8 bf16 {0.0, 1.0}
__device__ __forceinline__ bf16x8 expand8(unsigned int byte) {
    union { unsigned int u[4]; bf16x8 v; } r;
    #pragma unroll
    for (int p = 0; p < 4; p++) {
        unsigned int lo = ((byte >> (2*p)) & 1u) * 0x3F80u;
        unsigned int hi = ((byte >> (2*p+1)) & 1u) * 0x3F80u;
        r.u[p] = lo | (hi << 16);
    }
    return r.v;
}

// ============ GEMM2: a2 = z1 @ (W2hi+W2lo).T + b2 via MFMA ============
// z1a layout: [b][w][t] words (bit = neuron offset within word w)
__global__ __launch_bounds__(256, 2) void gemm2_mfma(
        const unsigned long long* __restrict__ z1a,
        const unsigned short* __restrict__ w2frag,
        const float* __restrict__ b2, float* __restrict__ a2, int c) {
    __shared__ unsigned short Bs[2][16384];
    const int tx = threadIdx.x;
    const int wave = tx >> 6, lane = tx & 63;
    const int wm = wave >> 1, wn = wave & 1;
    const int ko = lane >> 4, ln = lane & 15;
    const int bm = blockIdx.x;
    const int bn = blockIdx.y;
    const int t_l = bm >> 4;
    const int b0 = (bm & 15) * 256 + wm * 128;
    const int t  = c * CH + t_l;

    f32x4 acc[8][4];
    #pragma unroll
    for (int mt = 0; mt < 8; mt++)
        #pragma unroll
        for (int nt = 0; nt < 4; nt++) acc[mt][nt] = (f32x4){0.f,0.f,0.f,0.f};

    const size_t zrowbase = (size_t)(b0 + ln) * 3072 + t;   // + row*3072 + w*128
    const unsigned short* sgbase = w2frag + (size_t)bn * 16384 + wave * 4096 + lane * 8;
    #define STAGE_B(w_, buf_) do {                                           \
        const unsigned short* s_ = sgbase + (size_t)(w_) * 32768;            \
        unsigned short* d_ = &Bs[buf_][wave * 4096];                         \
        _Pragma("unroll")                                                    \
        for (int j_ = 0; j_ < 8; j_++)                                       \
            gload_lds16(s_ + j_ * 512, d_ + j_ * 512);                       \
    } while (0)

    STAGE_B(0, 0);
    __syncthreads();

    for (int w = 0; w < 24; w++) {
        const int buf = w & 1;
        if (w < 23) STAGE_B(w + 1, buf ^ 1);
        unsigned long long zw[8];
        #pragma unroll
        for (int mt = 0; mt < 8; mt++)
            zw[mt] = z1a[zrowbase + (size_t)(mt * 16) * 3072 + w * 128];
        #pragma unroll
        for (int ks = 0; ks < 2; ks++) {
            bf16x8 af[8];
            #pragma unroll
            for (int mt = 0; mt < 8; mt++)
                af[mt] = expand8((unsigned int)(zw[mt] >> (ks * 32 + ko * 8)) & 0xFFu);
            #pragma unroll
            for (int nt = 0; nt < 4; nt++) {
                #pragma unroll
                for (int s = 0; s < 2; s++) {
                    bf16x8 bf = *(const bf16x8*)&Bs[buf][ks*8192 + (wn*4 + nt)*1024 + s*512 + lane*8];
                    #pragma unroll
                    for (int mt = 0; mt < 8; mt++)
                        acc[mt][nt] = __builtin_amdgcn_mfma_f32_16x16x32_bf16(af[mt], bf, acc[mt][nt], 0, 0, 0);
                }
            }
        }
        __syncthreads();
    }
    #pragma unroll
    for (int nt = 0; nt < 4; nt++) {
        const int o = bn * 128 + wn * 64 + nt * 16 + ln;
        const float bias = b2[o];
        #pragma unroll
        for (int mt = 0; mt < 8; mt++) {
            #pragma unroll
            for (int r = 0; r < 4; r++) {
                const int brow = b0 + mt * 16 + ko * 4 + r;
                a2[((size_t)t_l * BSZ + brow) * N2 + o] = acc[mt][nt][r] + bias;
            }
        }
    }
    #undef STAGE_B
}

// ============ LIF2 spikes only ============
__global__ __launch_bounds__(256) void lif2z_kernel(
        const float* __restrict__ a2, float* __restrict__ v2s, float* __restrict__ i2s,
        unsigned long long* __restrict__ z2bits, int c) {
    const int b = blockIdx.x;
    const int n = threadIdx.x;
    const int wid = n >> 6, lane = n & 63;
    float v2, i2;
    if (c == 0) { v2 = 0.f; i2 = 0.f; }
    else { v2 = v2s[(size_t)b * N2 + n]; i2 = i2s[(size_t)b * N2 + n]; }
    for (int tl = 0; tl < CH; tl++) {
        float a = a2[((size_t)tl * BSZ + b) * N2 + n];
        float vd = v2 + DVM * (i2 - v2);
        bool z = (vd - VTH) > 0.f;
        unsigned long long m = __ballot(z);
        if (lane == 0) z2bits[((size_t)(c * CH + tl) * BSZ + b) * 4 + wid] = m;
        v2 = z ? 0.f : vd;
        i2 = DIS * i2 + a;
    }
    v2s[(size_t)b * N2 + n] = v2;
    i2s[(size_t)b * N2 + n] = i2;
}

// ============ GEMM3: a3 = z2 @ W3.T + b3 (bit-dot) ============
__global__ __launch_bounds__(256) void gemm3_kernel(
        const unsigned long long* __restrict__ z2bits, const float* __restrict__ W3,
        const float* __restrict__ b3, float* __restrict__ a3) {
    const int idx = blockIdx.x * 256 + threadIdx.x;
    unsigned long long zw[4];
    #pragma unroll
    for (int g = 0; g < 4; g++) zw[g] = z2bits[(size_t)idx * 4 + g];
    float acc[NO];
    #pragma unroll
    for (int o = 0; o < NO; o++) acc[o] = b3[o];
    #pragma unroll
    for (int g = 0; g < 4; g++) {
        unsigned long long wg = zw[g];
        for (int kb = 0; kb < 64; kb++) {
            float bit = (float)((wg >> kb) & 1ull);
            #pragma unroll
            for (int o = 0; o < NO; o++)
                acc[o] = fmaf(bit, W3[o * N2 + g * 64 + kb], acc[o]);
        }
    }
    #pragma unroll
    for (int o = 0; o < NO; o++) a3[(size_t)idx * NO + o] = acc[o];
}

// ============ LI + max over time ============
__global__ __launch_bounds__(256) void li_kernel(
        const float* __restrict__ a3, const float* __restrict__ noise,
        float* __restrict__ out) {
    const int idx = blockIdx.x * 256 + threadIdx.x;
    if (idx >= BSZ * NO) return;
    float vl = 0.f, il = 0.f, mx = -1e30f;
    for (int t = 0; t < SEQ; t++) {
        float a = a3[(size_t)t * (BSZ * NO) + idx];
        float vn = vl + DVM * (il - vl);
        il = DIS * il + a;
        vl = vn;
        mx = fmaxf(mx, vl + 0.001f * noise[(size_t)t * (BSZ * NO) + idx]);
    }
    out[idx] = mx;
}

// ---------------- host ----------------
extern "C" void kernel_launch(void* const* d_in, const int* in_sizes, int n_in,
                              void* d_out, int out_size, void* d_ws, size_t ws_size,
                              hipStream_t stream) {
    const float* x     = (const float*)d_in[0];
    const float* W1    = (const float*)d_in[1];
    const float* b1    = (const float*)d_in[2];
    const float* W2    = (const float*)d_in[3];
    const float* b2    = (const float*)d_in[4];
    const float* W3    = (const float*)d_in[5];
    const float* b3    = (const float*)d_in[6];
    const float* noise = (const float*)d_in[7];
    float* out = (float*)d_out;

    char* ws = (char*)d_ws;
    float* inp1 = (float*)(ws + OFF_INP1);
    float* a2   = (float*)(ws + OFF_A2);
    float* a3   = (float*)(ws + OFF_A3);
    unsigned short* xf  = (unsigned short*)(ws + OFF_XF);
    unsigned short* w1f = (unsigned short*)(ws + OFF_W1F);
    unsigned long long* z1 = (unsigned long long*)(ws + OFF_Z1);
    float* v2 = (float*)(ws + OFF_V2);
    float* i2 = (float*)(ws + OFF_I2);
    unsigned long long* z2 = (unsigned long long*)(ws + OFF_Z2);
    unsigned short* w2f = (unsigned short*)(ws + OFF_W2F);

    dim3 blk(256);
    prep_x_kernel<<<dim3(6144), blk, 0, stream>>>(x, xf);
    prep_w1_kernel<<<dim3(2304), blk, 0, stream>>>(W1, w1f);
    prep_w2_kernel<<<dim3(192), blk, 0, stream>>>(W2, w2f);
    gemm1_mfma<<<dim3(384), blk, 0, stream>>>(xf, w1f, b1, inp1);
    lif1_kernel<<<dim3(N1/256, BSZ), blk, 0, stream>>>(inp1, z1);   // z1 overlays xf (dead)
    for (int c = 0; c < NCHUNK; c++) {
        gemm2_mfma<<<dim3(256, 2), blk, 0, stream>>>(z1, w2f, b2, a2, c);
        lif2z_kernel<<<dim3(BSZ), blk, 0, stream>>>(a2, v2, i2, z2, c);  // v2/i2/z2 overlay w1f (dead)
    }
    gemm3_kernel<<<dim3(SEQ * BSZ / 256), blk, 0, stream>>>(z2, W3, b3, a3);
    li_kernel<<<dim3((BSZ * NO + 255) / 256), blk, 0, stream>>>(a3, noise, out);
}